// Round 13
// baseline (176.379 us; speedup 1.0000x reference)
//
#include <hip/hip_runtime.h>
#include <hip/hip_bf16.h>

// Problem constants
#define B_   256
#define L_   64
#define DT_  768
#define DH_  128
#define AL_  48
#define DTE_ 64
#define H_   8
#define NL_  3
#define DFF_ 512

typedef __attribute__((ext_vector_type(4))) float f32x4;
typedef __attribute__((ext_vector_type(4))) unsigned int u32x4;
typedef __attribute__((ext_vector_type(2))) unsigned int u32x2;
typedef __attribute__((ext_vector_type(8))) short short8;

__device__ inline unsigned short f2bf(float f) {
    union { float f; unsigned u; } v; v.f = f;
    unsigned r = (v.u + 0x7FFFu + ((v.u >> 16) & 1u)) >> 16;
    return (unsigned short)r;
}
__device__ inline unsigned f2bf2(float a, float b) {
    return (unsigned)f2bf(a) | ((unsigned)f2bf(b) << 16);
}
__device__ inline float bf2f(unsigned short u) {
    union { unsigned u; float f; } v; v.u = ((unsigned)u) << 16; return v.f;
}
__device__ inline short8 ldg8(const unsigned short* p) {
    union { short8 s; u32x4 v; } r;
    r.v = *(const u32x4*)p;
    return r.s;
}
// packed f16 helpers
__device__ inline unsigned pk_f16(float a, float b) {
    unsigned r;
    asm("v_cvt_pkrtz_f16_f32 %0, %1, %2" : "=v"(r) : "v"(a), "v"(b));
    return r;
}
__device__ inline unsigned pk_max(unsigned a, unsigned b) {
    unsigned r;
    asm("v_pk_max_f16 %0, %1, %2" : "=v"(r) : "v"(a), "v"(b));
    return r;
}
__device__ inline float f16_lo(unsigned h) {
    float f; asm("v_cvt_f32_f16 %0, %1" : "=v"(f) : "v"(h)); return f;
}
__device__ inline float f16_hi(unsigned h) {
    float f; unsigned t = h >> 16;
    asm("v_cvt_f32_f16 %0, %1" : "=v"(f) : "v"(t)); return f;
}

// per-wave attention scratch for the fused layer kernel
struct PWS {
    union QP {
        struct { unsigned short qM[16 * 40]; unsigned short kM[48 * 40]; } qk; // 5120B
        unsigned short P[16 * 64];                                            // 2048B
    } u;
    unsigned short vT[16 * 72];                                               // 2304B
    float sL[16 * 52];                                                        // 3328B
};

// ====== Weight prep (fp32 [K][N] -> bf16 Wt [N][K]) + q_all prep (last block) =
struct TEnt { const float* src; int dstOff; int K; int N; int tile0; };
struct TTab { TEnt e[19]; };

__global__ __launch_bounds__(256) void prep_weights_kernel(
    TTab tab, int ntile, unsigned short* __restrict__ wt,
    const float* __restrict__ te_w, const float* __restrict__ te_b,
    const float* __restrict__ wq, float* __restrict__ q_allG)
{
    __shared__ unsigned short lds[64][72];
    __shared__ float qte[AL_ * 68];
    int tid = threadIdx.x;
    if ((int)blockIdx.x >= ntile) {
        for (int i = tid; i < AL_ * 64; i += 256) {
            int a = i >> 6, j = i & 63;
            float lin = fmaf((float)a, te_w[j], te_b[j]);
            qte[a * 68 + j] = (j == 0) ? lin : __sinf(lin);
        }
        __syncthreads();
        for (int i = tid; i < AL_ * 64; i += 256) {
            int a = i >> 6, d = i & 63;
            float s0 = 0.f, s1 = 0.f, s2 = 0.f, s3 = 0.f;
            for (int j = 0; j < 64; j += 4) {
                s0 = fmaf(qte[a * 68 + j],     wq[j * 64 + d],       s0);
                s1 = fmaf(qte[a * 68 + j + 1], wq[(j + 1) * 64 + d], s1);
                s2 = fmaf(qte[a * 68 + j + 2], wq[(j + 2) * 64 + d], s2);
                s3 = fmaf(qte[a * 68 + j + 3], wq[(j + 3) * 64 + d], s3);
            }
            q_allG[i] = (s0 + s1) + (s2 + s3);
        }
        return;
    }
    int ei = 0;
    #pragma unroll
    for (int j = 1; j < 19; ++j) if ((int)blockIdx.x >= tab.e[j].tile0) ei = j;
    TEnt e = tab.e[ei];
    int t = blockIdx.x - e.tile0;
    int tilesK = e.K >> 6;
    int tk = t % tilesK, tn = t / tilesK;
    #pragma unroll
    for (int p = 0; p < 16; ++p) {
        int kk = p * 4 + (tid >> 6);
        int n = tid & 63;
        float v = e.src[(size_t)(tk * 64 + kk) * e.N + tn * 64 + n];
        lds[n][kk] = f2bf(v);
    }
    __syncthreads();
    #pragma unroll
    for (int p = 0; p < 2; ++p) {
        int c = p * 256 + tid;
        int n = c >> 3, q = c & 7;
        u32x4 v = *(const u32x4*)(&lds[n][q * 8]);
        *(u32x4*)(&wt[(size_t)e.dstOff + (size_t)(tn * 64 + n) * e.K + tk * 64 + q * 8]) = v;
    }
}

// ====== bf16 MFMA GEMM (proj): B-frags direct from L2, BK=128, BM=32 =========
__global__ __launch_bounds__(256) void gemm_proj_kernel(
    const float* __restrict__ A, const unsigned short* __restrict__ Wt,
    const float* __restrict__ bias, unsigned short* __restrict__ C,
    int M, int N, int K)
{
    __shared__ unsigned short As[32 * 128];
    int tid = threadIdx.x;
    int bm = blockIdx.x * 32;
    int wave = tid >> 6, lane = tid & 63;
    int g = lane >> 4, r16 = lane & 15;

    f32x4 acc[2][2] = {};

    for (int k0 = 0; k0 < K; k0 += 128) {
        {
            int row = tid >> 3, c16 = (tid & 7) * 16;
            const float* Ap = &A[(size_t)(bm + row) * K + k0 + c16];
            f32x4 v0 = *(const f32x4*)(Ap);
            f32x4 v1 = *(const f32x4*)(Ap + 4);
            f32x4 v2 = *(const f32x4*)(Ap + 8);
            f32x4 v3 = *(const f32x4*)(Ap + 12);
            u32x4 w0, w1;
            w0[0] = f2bf2(v0[0], v0[1]); w0[1] = f2bf2(v0[2], v0[3]);
            w0[2] = f2bf2(v1[0], v1[1]); w0[3] = f2bf2(v1[2], v1[3]);
            w1[0] = f2bf2(v2[0], v2[1]); w1[1] = f2bf2(v2[2], v2[3]);
            w1[2] = f2bf2(v3[0], v3[1]); w1[3] = f2bf2(v3[2], v3[3]);
            int cA = c16, cB = c16 + 8;
            *(u32x4*)(&As[row * 128 + (cA & 64) + ((cA & 63) ^ ((row & 7) << 3))]) = w0;
            *(u32x4*)(&As[row * 128 + (cB & 64) + ((cB & 63) ^ ((row & 7) << 3))]) = w1;
        }
        __syncthreads();
        #pragma unroll
        for (int kk = 0; kk < 4; ++kk) {
            int co = kk * 32 + g * 8;
            short8 af[2];
            #pragma unroll
            for (int mi = 0; mi < 2; ++mi) {
                int rr = mi * 16 + r16;
                af[mi] = *(const short8*)(&As[rr * 128 + (co & 64) + ((co & 63) ^ ((rr & 7) << 3))]);
            }
            #pragma unroll
            for (int q = 0; q < 2; ++q) {
                int ni = wave * 2 + q;
                short8 bf = ldg8(&Wt[(size_t)(ni * 16 + r16) * K + k0 + co]);
                acc[0][q] = __builtin_amdgcn_mfma_f32_16x16x32_bf16(af[0], bf, acc[0][q], 0, 0, 0);
                acc[1][q] = __builtin_amdgcn_mfma_f32_16x16x32_bf16(af[1], bf, acc[1][q], 0, 0, 0);
            }
        }
        __syncthreads();
    }
    #pragma unroll
    for (int q = 0; q < 2; ++q) {
        int col = (wave * 2 + q) * 16 + r16;
        float bv = bias[col];
        #pragma unroll
        for (int mi = 0; mi < 2; ++mi) {
            #pragma unroll
            for (int r = 0; r < 4; ++r) {
                int row = bm + mi * 16 + g * 4 + r;
                C[(size_t)row * N + col] = f2bf(acc[mi][q][r] + bv);
            }
        }
    }
}

// ================= First attention: block = (b, half of 48 alpha rows) ========
__global__ __launch_bounds__(256) void first_attn_kernel(
    const float* __restrict__ note_times, const int* __restrict__ note_counts,
    const float* __restrict__ te_w, const float* __restrict__ te_b,
    const float* __restrict__ wk, const float* __restrict__ q_all,
    const unsigned short* __restrict__ note_emb,
    float* __restrict__ x_out, unsigned short* __restrict__ xbf_out)
{
    __shared__ union RU {
        float kkL[64 * 68];
        unsigned short E[32 * 256];
        struct { unsigned short As[32 * 64]; unsigned short Bs[128 * 64]; } mm;
    } ru;
    __shared__ float rsL[32][8];

    const int bx = blockIdx.x;
    const int b = bx >> 1, a0 = (bx & 1) * 24;
    const int tid = threadIdx.x, lane = tid & 63;
    const int wv = __builtin_amdgcn_readfirstlane(tid >> 6);
    const int g = lane >> 4, r16 = lane & 15;
    const int nc = note_counts[b];

    float kte[64];
    {
        float t = note_times[b * 64 + lane];
        #pragma unroll
        for (int j = 0; j < 64; ++j) {
            float lin = fmaf(t, te_w[j], te_b[j]);
            kte[j] = (j == 0) ? lin : __sinf(lin);
        }
    }
    {
        float kvp[16] = {};
        #pragma unroll
        for (int j = 0; j < 64; ++j) {
            #pragma unroll
            for (int dd = 0; dd < 16; ++dd)
                kvp[dd] = fmaf(kte[j], wk[j * 64 + wv * 16 + dd], kvp[dd]);
        }
        #pragma unroll
        for (int q4 = 0; q4 < 4; ++q4)
            *(f32x4*)(&ru.kkL[lane * 68 + wv * 16 + q4 * 4]) = *(const f32x4*)(&kvp[q4 * 4]);
    }
    __syncthreads();
    float kv[64];
    #pragma unroll
    for (int q4 = 0; q4 < 16; ++q4)
        *(f32x4*)(&kv[q4 * 4]) = *(const f32x4*)(&ru.kkL[lane * 68 + q4 * 4]);
    __syncthreads();

    float abar[6] = {};
    const float scale = 0.35355339059327373f; // 1/sqrt(8)
    #pragma unroll
    for (int p = 0; p < 2; ++p) {
        float e_reg[6][4];
        #pragma unroll
        for (int i = 0; i < 6; ++i) {
            int a = wv * 6 + i;
            float s[4];
            #pragma unroll
            for (int h = 0; h < 4; ++h) {
                float acc = 0.f;
                #pragma unroll
                for (int d = 0; d < 8; ++d)
                    acc = fmaf(q_all[(a0 + a) * 64 + p * 32 + h * 8 + d],
                               kv[p * 32 + h * 8 + d], acc);
                s[h] = (lane < nc) ? acc * scale : -1e9f;
            }
            unsigned m0 = pk_f16(s[0], s[1]);
            unsigned m1 = pk_f16(s[2], s[3]);
            #pragma unroll
            for (int st = 32; st >= 1; st >>= 1) {
                m0 = pk_max(m0, (unsigned)__shfl_xor((int)m0, st));
                m1 = pk_max(m1, (unsigned)__shfl_xor((int)m1, st));
            }
            float mm[4] = { f16_lo(m0), f16_hi(m0), f16_lo(m1), f16_hi(m1) };
            #pragma unroll
            for (int h = 0; h < 4; ++h) {
                float e = __expf(s[h] - mm[h]);
                e_reg[i][h] = e;
                int k = h * 64 + lane;
                ru.E[a * 256 + (k ^ ((a & 7) << 3))] = f2bf(e);
            }
        }
        __syncthreads();
        if (wv < 2) {
            f32x4 acc = {0.f, 0.f, 0.f, 0.f};
            #pragma unroll
            for (int ks = 0; ks < 8; ++ks) {
                int row = wv * 16 + r16;
                short8 af = *(const short8*)(&ru.E[row * 256 + ((ks * 32 + g * 8) ^ ((row & 7) << 3))]);
                short bb = (r16 == (ks >> 1)) ? (short)0x3F80 : (short)0;
                short8 bf = { bb, bb, bb, bb, bb, bb, bb, bb };
                acc = __builtin_amdgcn_mfma_f32_16x16x32_bf16(af, bf, acc, 0, 0, 0);
            }
            if (r16 < 4) {
                #pragma unroll
                for (int r = 0; r < 4; ++r)
                    rsL[wv * 16 + g * 4 + r][p * 4 + r16] = 0.125f / fmaxf(acc[r], 1e-20f);
            }
        }
        __syncthreads();
        #pragma unroll
        for (int i = 0; i < 6; ++i) {
            int a = wv * 6 + i;
            f32x4 rv = *(const f32x4*)(&rsL[a][p * 4]);
            abar[i] = fmaf(e_reg[i][0], rv[0], abar[i]);
            abar[i] = fmaf(e_reg[i][1], rv[1], abar[i]);
            abar[i] = fmaf(e_reg[i][2], rv[2], abar[i]);
            abar[i] = fmaf(e_reg[i][3], rv[3], abar[i]);
        }
    }
    {
        int l = tid & 63;
        #pragma unroll
        for (int pp = 0; pp < 4; ++pp) {
            int c = pp * 4 + (tid >> 6);
            u32x4 v = *(const u32x4*)(&note_emb[((size_t)b * 64 + l) * 128 + c * 8]);
            #pragma unroll
            for (int j = 0; j < 8; ++j) {
                unsigned short h16 = (unsigned short)((j & 1) ? (v[j >> 1] >> 16) : (v[j >> 1] & 0xffff));
                int f = c * 8 + j;
                ru.mm.Bs[f * 64 + (l ^ ((f & 7) << 3))] = h16;
            }
        }
    }
    #pragma unroll
    for (int i = 0; i < 6; ++i) {
        int a = wv * 6 + i;
        ru.mm.As[a * 64 + (lane ^ ((a & 7) << 3))] = f2bf(abar[i]);
    }
    __syncthreads();

    f32x4 pv[4] = {};
    #pragma unroll
    for (int q = 0; q < 4; ++q) {
        int f = wv * 4 + q, mi = f >> 3, ni = f & 7;
        #pragma unroll
        for (int ks = 0; ks < 2; ++ks) {
            int co = ks * 32 + g * 8;
            int raw = mi * 16 + r16, rb = ni * 16 + r16;
            short8 af = *(const short8*)(&ru.mm.As[raw * 64 + (co ^ ((raw & 7) << 3))]);
            short8 bf = *(const short8*)(&ru.mm.Bs[rb * 64 + (co ^ ((rb & 7) << 3))]);
            pv[q] = __builtin_amdgcn_mfma_f32_16x16x32_bf16(af, bf, pv[q], 0, 0, 0);
        }
    }
    #pragma unroll
    for (int q = 0; q < 4; ++q) {
        int f = wv * 4 + q, mi = f >> 3, ni = f & 7;
        #pragma unroll
        for (int r = 0; r < 4; ++r) {
            int row = mi * 16 + g * 4 + r;
            if (row < 24) {
                float v = (nc > 0) ? pv[q][r] : 0.f;
                size_t o = ((size_t)b * AL_ + a0 + row) * 128 + ni * 16 + r16;
                x_out[o] = v;
                xbf_out[o] = f2bf(v);
            }
        }
    }
}

// ====== Fused transformer layer: block = 16 rows of one batch =================
// attention (wave-private, barrier-free) + wo + LN1 + FFN + LN2 (+head if last)
__global__ __launch_bounds__(256) void fused_layer_kernel(
    const float* __restrict__ x, const unsigned short* __restrict__ xbf,
    const unsigned short* __restrict__ Wl,
    const float* __restrict__ b1, const float* __restrict__ b2,
    const float* __restrict__ g1, const float* __restrict__ be1,
    const float* __restrict__ g2, const float* __restrict__ be2,
    float* __restrict__ xout, unsigned short* __restrict__ xbfout,
    int last,
    const float* __restrict__ cw1, const float* __restrict__ cb1,
    const float* __restrict__ cw2, const float* __restrict__ cb2,
    float* __restrict__ outp)
{
    __shared__ union UF {
        struct { unsigned short Xs[48 * 128]; PWS pw[4]; } at;  // 12288 + 43008
        unsigned short hid[16 * 512];                            // 16384
        float Cs[16 * 132];                                      // 8448
    } uf;
    __shared__ unsigned short AO[16 * 128];                      // 4096

    const int tid = threadIdx.x, lane = tid & 63;
    const int wv = __builtin_amdgcn_readfirstlane(tid >> 6);
    const int g = lane >> 4, r16 = lane & 15;
    int b, lr;
    if (last) { b = blockIdx.x; lr = 32; }
    else { b = blockIdx.x / 3; lr = (blockIdx.x - b * 3) * 16; }
    const int row0 = b * 48 + lr;

    // prefetch LN1 residual (fp32) into regs (hidden under staging + attention)
    float res0[4], res1[4];
    #pragma unroll
    for (int rr = 0; rr < 4; ++rr) {
        int row = wv * 4 + rr;
        size_t go = (size_t)(row0 + row) * 128;
        res0[rr] = x[go + lane];
        res1[rr] = x[go + 64 + lane];
    }

    // stage full batch Xs (48x128 bf16, swizzled)
    #pragma unroll
    for (int p = 0; p < 3; ++p) {
        int i = p * 256 + tid;
        int a = i >> 4, c = (i & 15) * 8;
        u32x4 v = *(const u32x4*)(&xbf[((size_t)b * 48 + a) * 128 + c]);
        *(u32x4*)(&uf.at.Xs[a * 128 + (c & 64) + ((c & 63) ^ ((a & 7) << 3))]) = v;
    }
    __syncthreads();

    PWS* pw = &uf.at.pw[wv];

    // attention: wave wv handles heads wv and wv+4; no cross-wave sync inside
    for (int hi = 0; hi < 2; ++hi) {
        int h = wv + hi * 4;
        // zero pads (per-wave; P overlay corrupted qk pads last iteration)
        #pragma unroll
        for (int i2 = 0; i2 < 12; ++i2) pw->u.qk.kM[(i2 * 4 + g) * 40 + 16 + r16] = 0;
        #pragma unroll
        for (int i2 = 0; i2 < 4; ++i2)  pw->u.qk.qM[(i2 * 4 + g) * 40 + 16 + r16] = 0;
        #pragma unroll
        for (int i2 = 0; i2 < 4; ++i2)  pw->vT[(i2 * 4 + g) * 72 + 48 + r16] = 0;

        // q (16 rows) / k (48 rows) / v (48 rows) projections, B-frags from L2
        {
            const unsigned short* WmQ = Wl + 0 * 16384 + (size_t)(h * 16 + r16) * 128;
            const unsigned short* WmK = Wl + 1 * 16384 + (size_t)(h * 16 + r16) * 128;
            const unsigned short* WmV = Wl + 2 * 16384 + (size_t)(h * 16 + r16) * 128;
            f32x4 qa = {0.f, 0.f, 0.f, 0.f};
            f32x4 ka[3] = {}, va[3] = {};
            #pragma unroll
            for (int kq = 0; kq < 4; ++kq) {
                int co = kq * 32 + g * 8;
                short8 bq = ldg8(WmQ + co);
                short8 bk = ldg8(WmK + co);
                short8 bvv = ldg8(WmV + co);
                {
                    int rowx = lr + r16;
                    short8 af = *(const short8*)(&uf.at.Xs[rowx * 128 + (co & 64) + ((co & 63) ^ ((rowx & 7) << 3))]);
                    qa = __builtin_amdgcn_mfma_f32_16x16x32_bf16(af, bq, qa, 0, 0, 0);
                }
                #pragma unroll
                for (int mi = 0; mi < 3; ++mi) {
                    int rowx = mi * 16 + r16;
                    short8 af = *(const short8*)(&uf.at.Xs[rowx * 128 + (co & 64) + ((co & 63) ^ ((rowx & 7) << 3))]);
                    ka[mi] = __builtin_amdgcn_mfma_f32_16x16x32_bf16(af, bk, ka[mi], 0, 0, 0);
                    va[mi] = __builtin_amdgcn_mfma_f32_16x16x32_bf16(af, bvv, va[mi], 0, 0, 0);
                }
            }
            #pragma unroll
            for (int r = 0; r < 4; ++r)
                pw->u.qk.qM[(g * 4 + r) * 40 + r16] = f2bf(qa[r]);
            #pragma unroll
            for (int mi = 0; mi < 3; ++mi)
                #pragma unroll
                for (int r = 0; r < 4; ++r) {
                    int a = mi * 16 + g * 4 + r;
                    pw->u.qk.kM[a * 40 + r16] = f2bf(ka[mi][r]);
                    pw->vT[r16 * 72 + a] = f2bf(va[mi][r]);
                }
        }

        // scores: S[16][48], 1x3 frags, K=32 (zero-padded)
        #pragma unroll
        for (int ni = 0; ni < 3; ++ni) {
            f32x4 acc = {0.f, 0.f, 0.f, 0.f};
            short8 af = *(const short8*)(&pw->u.qk.qM[r16 * 40 + g * 8]);
            short8 bf = *(const short8*)(&pw->u.qk.kM[(ni * 16 + r16) * 40 + g * 8]);
            acc = __builtin_amdgcn_mfma_f32_16x16x32_bf16(af, bf, acc, 0, 0, 0);
            #pragma unroll
            for (int r = 0; r < 4; ++r)
                pw->sL[(g * 4 + r) * 52 + ni * 16 + r16] = acc[r] * 0.25f;
        }

        // softmax: 16 rows, 4-lane groups (all 64 lanes)
        {
            int row = lane >> 2, sub = lane & 3;
            f32x4 v0 = *(const f32x4*)(&pw->sL[row * 52 + sub * 4]);
            f32x4 v1 = *(const f32x4*)(&pw->sL[row * 52 + 16 + sub * 4]);
            f32x4 v2 = *(const f32x4*)(&pw->sL[row * 52 + 32 + sub * 4]);
            float m = fmaxf(fmaxf(fmaxf(v0[0], v0[1]), fmaxf(v0[2], v0[3])),
                            fmaxf(fmaxf(v1[0], v1[1]), fmaxf(v1[2], v1[3])));
            m = fmaxf(m, fmaxf(fmaxf(v2[0], v2[1]), fmaxf(v2[2], v2[3])));
            m = fmaxf(m, __shfl_xor(m, 1));
            m = fmaxf(m, __shfl_xor(m, 2));
            float e[12];
            #pragma unroll
            for (int j = 0; j < 4; ++j) {
                e[j]     = __expf(v0[j] - m);
                e[4 + j] = __expf(v1[j] - m);
                e[8 + j] = __expf(v2[j] - m);
            }
            float sum = 0.f;
            #pragma unroll
            for (int j = 0; j < 12; ++j) sum += e[j];
            sum += __shfl_xor(sum, 1);
            sum += __shfl_xor(sum, 2);
            float inv = __fdividef(1.f, sum);
            #pragma unroll
            for (int c = 0; c < 3; ++c) {
                u32x2 w;
                w[0] = f2bf2(e[c * 4 + 0] * inv, e[c * 4 + 1] * inv);
                w[1] = f2bf2(e[c * 4 + 2] * inv, e[c * 4 + 3] * inv);
                int col = c * 16 + sub * 4;
                *(u32x2*)(&pw->u.P[row * 64 + (col ^ ((row & 7) << 3))]) = w;
            }
            #pragma unroll
            for (int i2 = 0; i2 < 4; ++i2) {
                int a = i2 * 4 + g, c = 48 + r16;
                pw->u.P[a * 64 + (c ^ ((a & 7) << 3))] = 0;
            }
        }

        // PV: out[16][16], 1 frag, K=64 (padded) -> AO column slice h*16..
        {
            f32x4 acc = {0.f, 0.f, 0.f, 0.f};
            #pragma unroll
            for (int ks = 0; ks < 2; ++ks) {
                int co = ks * 32 + g * 8;
                short8 af = *(const short8*)(&pw->u.P[r16 * 64 + (co ^ ((r16 & 7) << 3))]);
                short8 bf = *(const short8*)(&pw->vT[r16 * 72 + co]);
                acc = __builtin_amdgcn_mfma_f32_16x16x32_bf16(af, bf, acc, 0, 0, 0);
            }
            #pragma unroll
            for (int r = 0; r < 4; ++r) {
                int a = g * 4 + r, c = h * 16 + r16;
                AO[a * 128 + (c & 64) + ((c & 63) ^ ((a & 7) << 3))] = f2bf(acc[r]);
            }
        }
    }
    __syncthreads();   // attention complete; at-region free, AO complete

    // wo GEMM: A = AO (16x128), 8 frags: wave does ni = wv*2 + {0,1}
    {
        f32x4 wacc[2] = {};
        #pragma unroll
        for (int q = 0; q < 2; ++q) {
            int ni = wv * 2 + q;
            const unsigned short* Wm = Wl + 3 * 16384 + (size_t)(ni * 16 + r16) * 128;
            #pragma unroll
            for (int kq = 0; kq < 4; ++kq) {
                int co = kq * 32 + g * 8;
                short8 af = *(const short8*)(&AO[r16 * 128 + (co & 64) + ((co & 63) ^ ((r16 & 7) << 3))]);
                short8 bf = ldg8(Wm + co);
                wacc[q] = __builtin_amdgcn_mfma_f32_16x16x32_bf16(af, bf, wacc[q], 0, 0, 0);
            }
        }
        #pragma unroll
        for (int q = 0; q < 2; ++q) {
            int ni = wv * 2 + q;
            #pragma unroll
            for (int r = 0; r < 4; ++r)
                uf.Cs[(g * 4 + r) * 132 + ni * 16 + r16] = wacc[q][r];
        }
    }
    __syncthreads();

    // LN1 (+residual from regs) -> AO (bf16, swizzled)
    #pragma unroll
    for (int rr = 0; rr < 4; ++rr) {
        int row = wv * 4 + rr;
        float v0 = uf.Cs[row * 132 + lane] + res0[rr];
        float v1 = uf.Cs[row * 132 + 64 + lane] + res1[rr];
        float sum = v0 + v1, sq = v0 * v0 + v1 * v1;
        #pragma unroll
        for (int o2 = 32; o2 >= 1; o2 >>= 1) {
            sum += __shfl_xor(sum, o2);
            sq  += __shfl_xor(sq, o2);
        }
        float mu = sum * (1.f / 128.f);
        float var = sq * (1.f / 128.f) - mu * mu;
        float rs = rsqrtf(var + 1e-5f);
        float o0 = (v0 - mu) * rs * g1[lane] + be1[lane];
        float o1 = (v1 - mu) * rs * g1[lane + 64] + be1[lane + 64];
        AO[row * 128 + (lane ^ ((row & 7) << 3))] = f2bf(o0);
        AO[row * 128 + 64 + (lane ^ ((row & 7) << 3))] = f2bf(o1);
    }
    __syncthreads();

    // hidden = relu(AO @ w1 + b1): wave owns cols [wv*128, +128)
    {
        f32x4 hacc[8] = {};
        #pragma unroll
        for (int nf = 0; nf < 8; ++nf) {
            int col = wv * 128 + nf * 16 + r16;
            const unsigned short* Wm = Wl + 65536 + (size_t)col * 128;
            #pragma unroll
            for (int kq = 0; kq < 4; ++kq) {
                int co = kq * 32 + g * 8;
                short8 bf = ldg8(Wm + co);
                short8 af = *(const short8*)(&AO[r16 * 128 + (co & 64) + ((co & 63) ^ ((r16 & 7) << 3))]);
                hacc[nf] = __builtin_amdgcn_mfma_f32_16x16x32_bf16(af, bf, hacc[nf], 0, 0, 0);
            }
        }
        #pragma unroll
        for (int nf = 0; nf < 8; ++nf) {
            int col = wv * 128 + nf * 16 + r16;
            float bv = b1[col];
            #pragma unroll
            for (int r = 0; r < 4; ++r) {
                int rowa = g * 4 + r;
                uf.hid[rowa * 512 + (col & 448) + ((col & 63) ^ ((rowa & 7) << 3))] =
                    f2bf(fmaxf(hacc[nf][r] + bv, 0.f));
            }
        }
    }
    __syncthreads();

    // y = hid @ w2 (K=512)
    f32x4 yacc[2] = {};
    #pragma unroll
    for (int q = 0; q < 2; ++q) {
        int ni = wv * 2 + q;
        const unsigned short* Wm = Wl + 131072 + (size_t)(ni * 16 + r16) * 512;
        #pragma unroll
        for (int kq = 0; kq < 16; ++kq) {
            int co = kq * 32 + g * 8;
            short8 af = *(const short8*)(&uf.hid[r16 * 512 + (co & 448) + ((co & 63) ^ ((r16 & 7) << 3))]);
            short8 bf = ldg8(Wm + co);
            yacc[q] = __builtin_amdgcn_mfma_f32_16x16x32_bf16(af, bf, yacc[q], 0, 0, 0);
        }
    }
    __syncthreads();  // hid reads done -> Cs overlay safe
    #pragma unroll
    for (int q = 0; q < 2; ++q) {
        int ni = wv * 2 + q;
        float bv = b2[ni * 16 + r16];
        #pragma unroll
        for (int r = 0; r < 4; ++r)
            uf.Cs[(g * 4 + r) * 132 + ni * 16 + r16] = yacc[q][r] + bv;
    }
    __syncthreads();

    // LN2 (+residual from AO bf16 LN1-output)
    #pragma unroll
    for (int rr = 0; rr < 4; ++rr) {
        int row = wv * 4 + rr;
        size_t go = (size_t)(row0 + row) * 128;
        float r0 = bf2f(AO[row * 128 + (lane ^ ((row & 7) << 3))]);
        float r1 = bf2f(AO[row * 128 + 64 + (lane ^ ((row & 7) << 3))]);
        float v0 = uf.Cs[row * 132 + lane] + r0;
        float v1 = uf.Cs[row * 132 + 64 + lane] + r1;
        float sum = v0 + v1, sq = v0 * v0 + v1 * v1;
        #pragma unroll
        for (int o2 = 32; o2 >= 1; o2 >>= 1) {
            sum += __shfl_xor(sum, o2);
            sq  += __shfl_xor(sq, o2);
        }
        float mu = sum * (1.f / 128.f);
        float var = sq * (1.f / 128.f) - mu * mu;
        float rs = rsqrtf(var + 1e-5f);
        float o0 = (v0 - mu) * rs * g2[lane] + be2[lane];
        float o1 = (v1 - mu) * rs * g2[lane + 64] + be2[lane + 64];
        if (!last) {
            xout[go + lane] = o0;
            xout[go + 64 + lane] = o1;
            xbfout[go + lane] = f2bf(o0);
            xbfout[go + 64 + lane] = f2bf(o1);
        } else {
            uf.Cs[row * 132 + lane] = o0;
            uf.Cs[row * 132 + 64 + lane] = o1;
        }
    }
    if (last) {
        __syncthreads();
        if (wv == 0) {
            float hj = cb1[lane];
            #pragma unroll 8
            for (int d = 0; d < 128; ++d)
                hj = fmaf(uf.Cs[15 * 132 + d], cw1[d * 64 + lane], hj);
            hj = fmaxf(hj, 0.f);
            float acc = hj * cw2[lane];
            #pragma unroll
            for (int o2 = 32; o2 >= 1; o2 >>= 1) acc += __shfl_xor(acc, o2);
            if (lane == 0) outp[blockIdx.x] = acc + cb2[0];
        }
    }
}

// ================= Launch =====================================================
extern "C" void kernel_launch(void* const* d_in, const int* in_sizes, int n_in,
                              void* d_out, int out_size, void* d_ws, size_t ws_size,
                              hipStream_t stream) {
    (void)in_sizes; (void)n_in; (void)out_size; (void)ws_size;
    const float* cls_emb    = (const float*)d_in[0];
    const float* note_times = (const float*)d_in[1];
    const int*   note_counts= (const int*)d_in[2];
    const float* proj_w     = (const float*)d_in[3];
    const float* proj_b     = (const float*)d_in[4];
    const float* te_w       = (const float*)d_in[5];
    const float* te_b       = (const float*)d_in[6];
    const float* wq         = (const float*)d_in[7];
    const float* wk         = (const float*)d_in[8];
    const float* tf_wq      = (const float*)d_in[9];
    const float* tf_wk      = (const float*)d_in[10];
    const float* tf_wv      = (const float*)d_in[11];
    const float* tf_wo      = (const float*)d_in[12];
    const float* tf_ln1_g   = (const float*)d_in[13];
    const float* tf_ln1_b   = (const float*)d_in[14];
    const float* tf_w1      = (const float*)d_in[15];
    const float* tf_b1      = (const float*)d_in[16];
    const float* tf_w2      = (const float*)d_in[17];
    const float* tf_b2      = (const float*)d_in[18];
    const float* tf_ln2_g   = (const float*)d_in[19];
    const float* tf_ln2_b   = (const float*)d_in[20];
    const float* cls_w1     = (const float*)d_in[21];
    const float* cls_b1     = (const float*)d_in[22];
    const float* cls_w2     = (const float*)d_in[23];
    const float* cls_b2     = (const float*)d_in[24];
    float* out = (float*)d_out;
    float* ws = (float*)d_ws;

    // workspace layout (float units)
    unsigned short* note_emb16 = (unsigned short*)(ws + 0);       // 1,048,576 f
    float* x        = ws + 1048576;                                // 1,572,864 f
    unsigned short* xbf    = (unsigned short*)(ws + 2621440);      // 786,432 f
    float* q_all    = ws + 3407872;                                // 3,072 f
    unsigned short* wt     = (unsigned short*)(ws + 3410944);      // 344,064 f

    TTab tab;
    int tile = 0, idx = 0;
    auto add = [&](const float* src, int dstOff, int K, int N) {
        tab.e[idx].src = src; tab.e[idx].dstOff = dstOff;
        tab.e[idx].K = K; tab.e[idx].N = N; tab.e[idx].tile0 = tile;
        tile += (K / 64) * (N / 64); ++idx;
    };
    add(proj_w, 0, DT_, DH_);
    int layerBase[NL_];
    for (int i = 0; i < NL_; ++i) {
        int base = 98304 + i * 196608;
        layerBase[i] = base;
        add(tf_wq + (size_t)i * DH_ * DH_, base,           DH_, DH_);
        add(tf_wk + (size_t)i * DH_ * DH_, base + 16384,   DH_, DH_);
        add(tf_wv + (size_t)i * DH_ * DH_, base + 32768,   DH_, DH_);
        add(tf_wo + (size_t)i * DH_ * DH_, base + 49152,   DH_, DH_);
        add(tf_w1 + (size_t)i * DH_ * DFF_, base + 65536,  DH_, DFF_);
        add(tf_w2 + (size_t)i * DFF_ * DH_, base + 131072, DFF_, DH_);
    }
    prep_weights_kernel<<<tile + 1, 256, 0, stream>>>(tab, tile, wt, te_w, te_b, wq, q_all);

    gemm_proj_kernel<<<(B_ * L_) / 32, 256, 0, stream>>>(
        cls_emb, wt, proj_b, note_emb16, B_ * L_, DH_, DT_);

    first_attn_kernel<<<B_ * 2, 256, 0, stream>>>(
        note_times, note_counts, te_w, te_b, wk, q_all, note_emb16, x, xbf);

    for (int i = 0; i < NL_; ++i) {
        int base = layerBase[i];
        int last = (i == NL_ - 1);
        fused_layer_kernel<<<last ? B_ : (B_ * 3), 256, 0, stream>>>(
            x, xbf, wt + base,
            tf_b1 + i * DFF_, tf_b2 + i * DH_,
            tf_ln1_g + i * DH_, tf_ln1_b + i * DH_,
            tf_ln2_g + i * DH_, tf_ln2_b + i * DH_,
            x, xbf,
            last, cls_w1, cls_b1, cls_w2, cls_b2, out);
    }
}

// Round 14
// 168.037 us; speedup vs baseline: 1.0496x; 1.0496x over previous
//
#include <hip/hip_runtime.h>
#include <hip/hip_bf16.h>

// Problem constants
#define B_   256
#define L_   64
#define DT_  768
#define DH_  128
#define AL_  48
#define DTE_ 64
#define H_   8
#define NL_  3
#define DFF_ 512

typedef __attribute__((ext_vector_type(4))) float f32x4;
typedef __attribute__((ext_vector_type(4))) unsigned int u32x4;
typedef __attribute__((ext_vector_type(2))) unsigned int u32x2;
typedef __attribute__((ext_vector_type(8))) short short8;

__device__ inline unsigned short f2bf(float f) {
    union { float f; unsigned u; } v; v.f = f;
    unsigned r = (v.u + 0x7FFFu + ((v.u >> 16) & 1u)) >> 16;
    return (unsigned short)r;
}
__device__ inline unsigned f2bf2(float a, float b) {
    return (unsigned)f2bf(a) | ((unsigned)f2bf(b) << 16);
}
__device__ inline float bf2f(unsigned short u) {
    union { unsigned u; float f; } v; v.u = ((unsigned)u) << 16; return v.f;
}
__device__ inline short8 ldg8(const unsigned short* p) {
    union { short8 s; u32x4 v; } r;
    r.v = *(const u32x4*)p;
    return r.s;
}
// packed f16 helpers
__device__ inline unsigned pk_f16(float a, float b) {
    unsigned r;
    asm("v_cvt_pkrtz_f16_f32 %0, %1, %2" : "=v"(r) : "v"(a), "v"(b));
    return r;
}
__device__ inline unsigned pk_max(unsigned a, unsigned b) {
    unsigned r;
    asm("v_pk_max_f16 %0, %1, %2" : "=v"(r) : "v"(a), "v"(b));
    return r;
}
__device__ inline float f16_lo(unsigned h) {
    float f; asm("v_cvt_f32_f16 %0, %1" : "=v"(f) : "v"(h)); return f;
}
__device__ inline float f16_hi(unsigned h) {
    float f; unsigned t = h >> 16;
    asm("v_cvt_f32_f16 %0, %1" : "=v"(f) : "v"(t)); return f;
}

// ====== Weight prep (fp32 [K][N] -> bf16 Wt [N][K]) + q_all prep (last block) =
struct TEnt { const float* src; int dstOff; int K; int N; int tile0; };
struct TTab { TEnt e[19]; };

__global__ __launch_bounds__(256) void prep_weights_kernel(
    TTab tab, int ntile, unsigned short* __restrict__ wt,
    const float* __restrict__ te_w, const float* __restrict__ te_b,
    const float* __restrict__ wq, float* __restrict__ q_allG)
{
    __shared__ unsigned short lds[64][72];
    __shared__ float qte[AL_ * 68];
    int tid = threadIdx.x;
    if ((int)blockIdx.x >= ntile) {
        for (int i = tid; i < AL_ * 64; i += 256) {
            int a = i >> 6, j = i & 63;
            float lin = fmaf((float)a, te_w[j], te_b[j]);
            qte[a * 68 + j] = (j == 0) ? lin : __sinf(lin);
        }
        __syncthreads();
        for (int i = tid; i < AL_ * 64; i += 256) {
            int a = i >> 6, d = i & 63;
            float s0 = 0.f, s1 = 0.f, s2 = 0.f, s3 = 0.f;
            for (int j = 0; j < 64; j += 4) {
                s0 = fmaf(qte[a * 68 + j],     wq[j * 64 + d],       s0);
                s1 = fmaf(qte[a * 68 + j + 1], wq[(j + 1) * 64 + d], s1);
                s2 = fmaf(qte[a * 68 + j + 2], wq[(j + 2) * 64 + d], s2);
                s3 = fmaf(qte[a * 68 + j + 3], wq[(j + 3) * 64 + d], s3);
            }
            q_allG[i] = (s0 + s1) + (s2 + s3);
        }
        return;
    }
    int ei = 0;
    #pragma unroll
    for (int j = 1; j < 19; ++j) if ((int)blockIdx.x >= tab.e[j].tile0) ei = j;
    TEnt e = tab.e[ei];
    int t = blockIdx.x - e.tile0;
    int tilesK = e.K >> 6;
    int tk = t % tilesK, tn = t / tilesK;
    #pragma unroll
    for (int p = 0; p < 16; ++p) {
        int kk = p * 4 + (tid >> 6);
        int n = tid & 63;
        float v = e.src[(size_t)(tk * 64 + kk) * e.N + tn * 64 + n];
        lds[n][kk] = f2bf(v);
    }
    __syncthreads();
    #pragma unroll
    for (int p = 0; p < 2; ++p) {
        int c = p * 256 + tid;
        int n = c >> 3, q = c & 7;
        u32x4 v = *(const u32x4*)(&lds[n][q * 8]);
        *(u32x4*)(&wt[(size_t)e.dstOff + (size_t)(tn * 64 + n) * e.K + tk * 64 + q * 8]) = v;
    }
}

// ====== bf16 MFMA GEMM (proj): B-frags direct from L2, BK=128, BM=32 =========
__global__ __launch_bounds__(256) void gemm_proj_kernel(
    const float* __restrict__ A, const unsigned short* __restrict__ Wt,
    const float* __restrict__ bias, unsigned short* __restrict__ C,
    int M, int N, int K)
{
    __shared__ unsigned short As[32 * 128];
    int tid = threadIdx.x;
    int bm = blockIdx.x * 32;
    int wave = tid >> 6, lane = tid & 63;
    int g = lane >> 4, r16 = lane & 15;

    f32x4 acc[2][2] = {};

    for (int k0 = 0; k0 < K; k0 += 128) {
        {
            int row = tid >> 3, c16 = (tid & 7) * 16;
            const float* Ap = &A[(size_t)(bm + row) * K + k0 + c16];
            f32x4 v0 = *(const f32x4*)(Ap);
            f32x4 v1 = *(const f32x4*)(Ap + 4);
            f32x4 v2 = *(const f32x4*)(Ap + 8);
            f32x4 v3 = *(const f32x4*)(Ap + 12);
            u32x4 w0, w1;
            w0[0] = f2bf2(v0[0], v0[1]); w0[1] = f2bf2(v0[2], v0[3]);
            w0[2] = f2bf2(v1[0], v1[1]); w0[3] = f2bf2(v1[2], v1[3]);
            w1[0] = f2bf2(v2[0], v2[1]); w1[1] = f2bf2(v2[2], v2[3]);
            w1[2] = f2bf2(v3[0], v3[1]); w1[3] = f2bf2(v3[2], v3[3]);
            int cA = c16, cB = c16 + 8;
            *(u32x4*)(&As[row * 128 + (cA & 64) + ((cA & 63) ^ ((row & 7) << 3))]) = w0;
            *(u32x4*)(&As[row * 128 + (cB & 64) + ((cB & 63) ^ ((row & 7) << 3))]) = w1;
        }
        __syncthreads();
        #pragma unroll
        for (int kk = 0; kk < 4; ++kk) {
            int co = kk * 32 + g * 8;
            short8 af[2];
            #pragma unroll
            for (int mi = 0; mi < 2; ++mi) {
                int rr = mi * 16 + r16;
                af[mi] = *(const short8*)(&As[rr * 128 + (co & 64) + ((co & 63) ^ ((rr & 7) << 3))]);
            }
            #pragma unroll
            for (int q = 0; q < 2; ++q) {
                int ni = wave * 2 + q;
                short8 bf = ldg8(&Wt[(size_t)(ni * 16 + r16) * K + k0 + co]);
                acc[0][q] = __builtin_amdgcn_mfma_f32_16x16x32_bf16(af[0], bf, acc[0][q], 0, 0, 0);
                acc[1][q] = __builtin_amdgcn_mfma_f32_16x16x32_bf16(af[1], bf, acc[1][q], 0, 0, 0);
            }
        }
        __syncthreads();
    }
    #pragma unroll
    for (int q = 0; q < 2; ++q) {
        int col = (wave * 2 + q) * 16 + r16;
        float bv = bias[col];
        #pragma unroll
        for (int mi = 0; mi < 2; ++mi) {
            #pragma unroll
            for (int r = 0; r < 4; ++r) {
                int row = bm + mi * 16 + g * 4 + r;
                C[(size_t)row * N + col] = f2bf(acc[mi][q][r] + bv);
            }
        }
    }
}

// ================= First attention: block = (b, half of 48 alpha rows) ========
__global__ __launch_bounds__(256) void first_attn_kernel(
    const float* __restrict__ note_times, const int* __restrict__ note_counts,
    const float* __restrict__ te_w, const float* __restrict__ te_b,
    const float* __restrict__ wk, const float* __restrict__ q_all,
    const unsigned short* __restrict__ note_emb,
    float* __restrict__ x_out, unsigned short* __restrict__ xbf_out)
{
    __shared__ union RU {
        float kkL[64 * 68];
        unsigned short E[32 * 256];
        struct { unsigned short As[32 * 64]; unsigned short Bs[128 * 64]; } mm;
    } ru;
    __shared__ float rsL[32][8];

    const int bx = blockIdx.x;
    const int b = bx >> 1, a0 = (bx & 1) * 24;
    const int tid = threadIdx.x, lane = tid & 63;
    const int wv = __builtin_amdgcn_readfirstlane(tid >> 6);
    const int g = lane >> 4, r16 = lane & 15;
    const int nc = note_counts[b];

    float kte[64];
    {
        float t = note_times[b * 64 + lane];
        #pragma unroll
        for (int j = 0; j < 64; ++j) {
            float lin = fmaf(t, te_w[j], te_b[j]);
            kte[j] = (j == 0) ? lin : __sinf(lin);
        }
    }
    {
        float kvp[16] = {};
        #pragma unroll
        for (int j = 0; j < 64; ++j) {
            #pragma unroll
            for (int dd = 0; dd < 16; ++dd)
                kvp[dd] = fmaf(kte[j], wk[j * 64 + wv * 16 + dd], kvp[dd]);
        }
        #pragma unroll
        for (int q4 = 0; q4 < 4; ++q4)
            *(f32x4*)(&ru.kkL[lane * 68 + wv * 16 + q4 * 4]) = *(const f32x4*)(&kvp[q4 * 4]);
    }
    __syncthreads();
    float kv[64];
    #pragma unroll
    for (int q4 = 0; q4 < 16; ++q4)
        *(f32x4*)(&kv[q4 * 4]) = *(const f32x4*)(&ru.kkL[lane * 68 + q4 * 4]);
    __syncthreads();

    float abar[6] = {};
    const float scale = 0.35355339059327373f; // 1/sqrt(8)
    #pragma unroll
    for (int p = 0; p < 2; ++p) {
        float e_reg[6][4];
        #pragma unroll
        for (int i = 0; i < 6; ++i) {
            int a = wv * 6 + i;
            float s[4];
            #pragma unroll
            for (int h = 0; h < 4; ++h) {
                float acc = 0.f;
                #pragma unroll
                for (int d = 0; d < 8; ++d)
                    acc = fmaf(q_all[(a0 + a) * 64 + p * 32 + h * 8 + d],
                               kv[p * 32 + h * 8 + d], acc);
                s[h] = (lane < nc) ? acc * scale : -1e9f;
            }
            unsigned m0 = pk_f16(s[0], s[1]);
            unsigned m1 = pk_f16(s[2], s[3]);
            #pragma unroll
            for (int st = 32; st >= 1; st >>= 1) {
                m0 = pk_max(m0, (unsigned)__shfl_xor((int)m0, st));
                m1 = pk_max(m1, (unsigned)__shfl_xor((int)m1, st));
            }
            float mm[4] = { f16_lo(m0), f16_hi(m0), f16_lo(m1), f16_hi(m1) };
            #pragma unroll
            for (int h = 0; h < 4; ++h) {
                float e = __expf(s[h] - mm[h]);
                e_reg[i][h] = e;
                int k = h * 64 + lane;
                ru.E[a * 256 + (k ^ ((a & 7) << 3))] = f2bf(e);
            }
        }
        __syncthreads();
        if (wv < 2) {
            f32x4 acc = {0.f, 0.f, 0.f, 0.f};
            #pragma unroll
            for (int ks = 0; ks < 8; ++ks) {
                int row = wv * 16 + r16;
                short8 af = *(const short8*)(&ru.E[row * 256 + ((ks * 32 + g * 8) ^ ((row & 7) << 3))]);
                short bb = (r16 == (ks >> 1)) ? (short)0x3F80 : (short)0;
                short8 bf = { bb, bb, bb, bb, bb, bb, bb, bb };
                acc = __builtin_amdgcn_mfma_f32_16x16x32_bf16(af, bf, acc, 0, 0, 0);
            }
            if (r16 < 4) {
                #pragma unroll
                for (int r = 0; r < 4; ++r)
                    rsL[wv * 16 + g * 4 + r][p * 4 + r16] = 0.125f / fmaxf(acc[r], 1e-20f);
            }
        }
        __syncthreads();
        #pragma unroll
        for (int i = 0; i < 6; ++i) {
            int a = wv * 6 + i;
            f32x4 rv = *(const f32x4*)(&rsL[a][p * 4]);
            abar[i] = fmaf(e_reg[i][0], rv[0], abar[i]);
            abar[i] = fmaf(e_reg[i][1], rv[1], abar[i]);
            abar[i] = fmaf(e_reg[i][2], rv[2], abar[i]);
            abar[i] = fmaf(e_reg[i][3], rv[3], abar[i]);
        }
    }
    {
        int l = tid & 63;
        #pragma unroll
        for (int pp = 0; pp < 4; ++pp) {
            int c = pp * 4 + (tid >> 6);
            u32x4 v = *(const u32x4*)(&note_emb[((size_t)b * 64 + l) * 128 + c * 8]);
            #pragma unroll
            for (int j = 0; j < 8; ++j) {
                unsigned short h16 = (unsigned short)((j & 1) ? (v[j >> 1] >> 16) : (v[j >> 1] & 0xffff));
                int f = c * 8 + j;
                ru.mm.Bs[f * 64 + (l ^ ((f & 7) << 3))] = h16;
            }
        }
    }
    #pragma unroll
    for (int i = 0; i < 6; ++i) {
        int a = wv * 6 + i;
        ru.mm.As[a * 64 + (lane ^ ((a & 7) << 3))] = f2bf(abar[i]);
    }
    __syncthreads();

    f32x4 pv[4] = {};
    #pragma unroll
    for (int q = 0; q < 4; ++q) {
        int f = wv * 4 + q, mi = f >> 3, ni = f & 7;
        #pragma unroll
        for (int ks = 0; ks < 2; ++ks) {
            int co = ks * 32 + g * 8;
            int raw = mi * 16 + r16, rb = ni * 16 + r16;
            short8 af = *(const short8*)(&ru.mm.As[raw * 64 + (co ^ ((raw & 7) << 3))]);
            short8 bf = *(const short8*)(&ru.mm.Bs[rb * 64 + (co ^ ((rb & 7) << 3))]);
            pv[q] = __builtin_amdgcn_mfma_f32_16x16x32_bf16(af, bf, pv[q], 0, 0, 0);
        }
    }
    #pragma unroll
    for (int q = 0; q < 4; ++q) {
        int f = wv * 4 + q, mi = f >> 3, ni = f & 7;
        #pragma unroll
        for (int r = 0; r < 4; ++r) {
            int row = mi * 16 + g * 4 + r;
            if (row < 24) {
                float v = (nc > 0) ? pv[q][r] : 0.f;
                size_t o = ((size_t)b * AL_ + a0 + row) * 128 + ni * 16 + r16;
                x_out[o] = v;
                xbf_out[o] = f2bf(v);
            }
        }
    }
}

// ====== Transformer self-attn: block = (b, 2 heads), 192 threads ==============
__global__ __launch_bounds__(192) void attn2_kernel(
    const unsigned short* __restrict__ xbf, const unsigned short* __restrict__ WtL,
    unsigned short* __restrict__ o)
{
    __shared__ unsigned short Xs[AL_ * 128];    // alive across both heads
    __shared__ float sL[AL_ * 52];
    __shared__ union UB {
        struct { unsigned short qM[AL_ * 40]; unsigned short kM[AL_ * 40]; } qk;
        unsigned short P[AL_ * 64];
    } ub;
    __shared__ unsigned short vT[16 * 72];
    int bid = blockIdx.x;
    int b = bid >> 2, h0 = (bid & 3) << 1;
    int tid = threadIdx.x, lane = tid & 63;
    int wv = __builtin_amdgcn_readfirstlane(tid >> 6);
    int g = lane >> 4, r16 = lane & 15;

    #pragma unroll
    for (int p = 0; p < 4; ++p) {
        int i = p * 192 + tid;
        int a = i >> 4, c = (i & 15) * 8;
        u32x4 v = *(const u32x4*)(&xbf[((size_t)b * AL_ + a) * 128 + c]);
        *(u32x4*)(&Xs[a * 128 + (c & 64) + ((c & 63) ^ ((a & 7) << 3))]) = v;
    }
    for (int i = tid; i < 256; i += 192) {
        int d = i >> 4, k2 = 48 + (i & 15);
        vT[d * 72 + k2] = 0;
    }
    __syncthreads();

    for (int hh = 0; hh < 2; ++hh) {
        int h = h0 + hh;
        // re-zero qM/kM pads (P overlay corrupted them last iteration)
        for (int i = tid; i < 768; i += 192) {
            int a = i >> 4, k2 = 16 + (i & 15);
            ub.qk.qM[a * 40 + k2] = 0;
            ub.qk.kM[a * 40 + k2] = 0;
        }
        // qkv: 3 waves, one matrix each (M=48, N=16, K=128)
        {
            f32x4 acc[3] = {};
            const unsigned short* Wm = WtL + wv * 16384 + (size_t)(h * 16) * 128;
            #pragma unroll
            for (int kq = 0; kq < 4; ++kq) {
                short8 bf = ldg8(&Wm[(size_t)r16 * 128 + kq * 32 + g * 8]);
                #pragma unroll
                for (int mi = 0; mi < 3; ++mi) {
                    int row = mi * 16 + r16;
                    int c = kq * 32 + g * 8;
                    short8 af = *(const short8*)(&Xs[row * 128 + (c & 64) + ((c & 63) ^ ((row & 7) << 3))]);
                    acc[mi] = __builtin_amdgcn_mfma_f32_16x16x32_bf16(af, bf, acc[mi], 0, 0, 0);
                }
            }
            #pragma unroll
            for (int mi = 0; mi < 3; ++mi) {
                #pragma unroll
                for (int r = 0; r < 4; ++r) {
                    int a = mi * 16 + g * 4 + r;
                    unsigned short hv = f2bf(acc[mi][r]);
                    if (wv == 0) ub.qk.qM[a * 40 + r16] = hv;
                    else if (wv == 1) ub.qk.kM[a * 40 + r16] = hv;
                    else vT[r16 * 72 + a] = hv;
                }
            }
        }
        __syncthreads();

        // scores: 9 frags (3m x 3n); this wave does m = wv
        {
            #pragma unroll
            for (int ni = 0; ni < 3; ++ni) {
                f32x4 acc = {0.f, 0.f, 0.f, 0.f};
                short8 af = *(const short8*)(&ub.qk.qM[(wv * 16 + r16) * 40 + g * 8]);
                short8 bf = *(const short8*)(&ub.qk.kM[(ni * 16 + r16) * 40 + g * 8]);
                acc = __builtin_amdgcn_mfma_f32_16x16x32_bf16(af, bf, acc, 0, 0, 0);
                #pragma unroll
                for (int r = 0; r < 4; ++r)
                    sL[(wv * 16 + g * 4 + r) * 52 + ni * 16 + r16] = acc[r] * 0.25f;
            }
        }
        __syncthreads();

        // distributed softmax: 4-lane group per row; P overlays dead qM/kM
        {
            int row = wv * 16 + (lane >> 2), sub = lane & 3;
            f32x4 v0 = *(const f32x4*)(&sL[row * 52 + sub * 4]);
            f32x4 v1 = *(const f32x4*)(&sL[row * 52 + 16 + sub * 4]);
            f32x4 v2 = *(const f32x4*)(&sL[row * 52 + 32 + sub * 4]);
            float m = fmaxf(fmaxf(fmaxf(v0[0], v0[1]), fmaxf(v0[2], v0[3])),
                            fmaxf(fmaxf(v1[0], v1[1]), fmaxf(v1[2], v1[3])));
            m = fmaxf(m, fmaxf(fmaxf(v2[0], v2[1]), fmaxf(v2[2], v2[3])));
            m = fmaxf(m, __shfl_xor(m, 1));
            m = fmaxf(m, __shfl_xor(m, 2));
            float e[12];
            #pragma unroll
            for (int j = 0; j < 4; ++j) {
                e[j]     = __expf(v0[j] - m);
                e[4 + j] = __expf(v1[j] - m);
                e[8 + j] = __expf(v2[j] - m);
            }
            float sum = 0.f;
            #pragma unroll
            for (int j = 0; j < 12; ++j) sum += e[j];
            sum += __shfl_xor(sum, 1);
            sum += __shfl_xor(sum, 2);
            float inv = __fdividef(1.f, sum);
            #pragma unroll
            for (int c = 0; c < 3; ++c) {
                u32x2 w;
                w[0] = f2bf2(e[c * 4 + 0] * inv, e[c * 4 + 1] * inv);
                w[1] = f2bf2(e[c * 4 + 2] * inv, e[c * 4 + 3] * inv);
                int col = c * 16 + sub * 4;
                *(u32x2*)(&ub.P[row * 64 + (col ^ ((row & 7) << 3))]) = w;
            }
            for (int i = tid; i < 768; i += 192) {
                int a = i >> 4, c = 48 + (i & 15);
                ub.P[a * 64 + (c ^ ((a & 7) << 3))] = 0;
            }
        }
        __syncthreads();

        // PV: out[a][d] = sum_a' P[a][a'] v[a'][d]; m-frag = wv, K=64 (padded)
        {
            f32x4 acc = {0.f, 0.f, 0.f, 0.f};
            #pragma unroll
            for (int ks = 0; ks < 2; ++ks) {
                int co = ks * 32 + g * 8;
                int rp = wv * 16 + r16;
                short8 af = *(const short8*)(&ub.P[rp * 64 + (co ^ ((rp & 7) << 3))]);
                short8 bf = *(const short8*)(&vT[r16 * 72 + co]);
                acc = __builtin_amdgcn_mfma_f32_16x16x32_bf16(af, bf, acc, 0, 0, 0);
            }
            #pragma unroll
            for (int r = 0; r < 4; ++r) {
                int a = wv * 16 + g * 4 + r;
                o[((size_t)b * AL_ + a) * 128 + h * 16 + r16] = f2bf(acc[r]);
            }
        }
        __syncthreads();
    }
}

// ====== Layer tail (ROWS rows/block): wo-GEMM + LN1 + FFN + LN2 (+head) =======
// Residual x loads hoisted to kernel entry (latency hidden under stage+woGEMM).
template<int ROWS>
__global__ __launch_bounds__(256) void layer_tail_kernel(
    const unsigned short* __restrict__ obuf, const unsigned short* __restrict__ Wl,
    const float* __restrict__ b1, const float* __restrict__ b2,
    const float* __restrict__ g1, const float* __restrict__ be1,
    const float* __restrict__ g2, const float* __restrict__ be2,
    float* __restrict__ x, unsigned short* __restrict__ xbf,
    int last, const float* __restrict__ cw1, const float* __restrict__ cb1,
    const float* __restrict__ cw2, const float* __restrict__ cb2,
    float* __restrict__ outp)
{
    constexpr int MR = ROWS / 16;
    constexpr int RW = ROWS / 4;
    __shared__ unsigned short OX[ROWS * 128];
    __shared__ union { unsigned short hid[ROWS * 512]; float Cs[ROWS * 132]; } u2;
    __shared__ float xr[ROWS * 132];
    const int tid = threadIdx.x, lane = tid & 63;
    const int wv = __builtin_amdgcn_readfirstlane(tid >> 6);
    const int g = lane >> 4, r16 = lane & 15;
    const int row0 = last ? ((int)blockIdx.x * 48 + 32) : ((int)blockIdx.x * ROWS);

    // prefetch LN1 residual (fp32 x) into registers -- issues before first barrier
    float res0[RW], res1[RW];
    #pragma unroll
    for (int rr = 0; rr < RW; ++rr) {
        int row = wv * RW + rr;
        size_t go = (size_t)(row0 + row) * 128;
        res0[rr] = x[go + lane];
        res1[rr] = x[go + 64 + lane];
    }

    #pragma unroll
    for (int p = 0; p < MR; ++p) {
        int i = p * 256 + tid;
        int a = i >> 4, c = (i & 15) * 8;
        u32x4 v = *(const u32x4*)(&obuf[(size_t)(row0 + a) * 128 + c]);
        *(u32x4*)(&OX[a * 128 + (c & 64) + ((c & 63) ^ ((a & 7) << 3))]) = v;
    }
    __syncthreads();

    // wo GEMM: 8*MR frags, wave does ni = wv*2 + {0,1}, mi < MR
    {
        f32x4 wacc[MR][2] = {};
        #pragma unroll
        for (int q = 0; q < 2; ++q) {
            int ni = wv * 2 + q;
            const unsigned short* Wm = Wl + 49152 + (size_t)(ni * 16 + r16) * 128;
            #pragma unroll
            for (int kq = 0; kq < 4; ++kq) {
                int co = kq * 32 + g * 8;
                short8 bf = ldg8(Wm + co);
                #pragma unroll
                for (int mi = 0; mi < MR; ++mi) {
                    int ra = mi * 16 + r16;
                    short8 af = *(const short8*)(&OX[ra * 128 + (co & 64) + ((co & 63) ^ ((ra & 7) << 3))]);
                    wacc[mi][q] = __builtin_amdgcn_mfma_f32_16x16x32_bf16(af, bf, wacc[mi][q], 0, 0, 0);
                }
            }
        }
        #pragma unroll
        for (int mi = 0; mi < MR; ++mi)
            #pragma unroll
            for (int q = 0; q < 2; ++q) {
                int ni = wv * 2 + q;
                #pragma unroll
                for (int r = 0; r < 4; ++r)
                    u2.Cs[(mi * 16 + g * 4 + r) * 132 + ni * 16 + r16] = wacc[mi][q][r];
            }
    }
    __syncthreads();

    // LN1 (+residual from regs)
    #pragma unroll
    for (int rr = 0; rr < RW; ++rr) {
        int row = wv * RW + rr;
        float v0 = u2.Cs[row * 132 + lane] + res0[rr];
        float v1 = u2.Cs[row * 132 + 64 + lane] + res1[rr];
        float sum = v0 + v1, sq = v0 * v0 + v1 * v1;
        #pragma unroll
        for (int o2 = 32; o2 >= 1; o2 >>= 1) {
            sum += __shfl_xor(sum, o2);
            sq  += __shfl_xor(sq, o2);
        }
        float mu = sum * (1.f / 128.f);
        float var = sq * (1.f / 128.f) - mu * mu;
        float rs = rsqrtf(var + 1e-5f);
        float o0 = (v0 - mu) * rs * g1[lane] + be1[lane];
        float o1 = (v1 - mu) * rs * g1[lane + 64] + be1[lane + 64];
        xr[row * 132 + lane] = o0;
        xr[row * 132 + 64 + lane] = o1;
        OX[row * 128 + (lane ^ ((row & 7) << 3))] = f2bf(o0);
        OX[row * 128 + 64 + (lane ^ ((row & 7) << 3))] = f2bf(o1);
    }
    __syncthreads();

    // hidden = relu(Xs @ w1 + b1): wave owns cols [wv*128, +128)
    {
        f32x4 hacc[MR][8] = {};
        #pragma unroll
        for (int nf = 0; nf < 8; ++nf) {
            int col = wv * 128 + nf * 16 + r16;
            const unsigned short* Wm = Wl + 65536 + (size_t)col * 128;
            #pragma unroll
            for (int kq = 0; kq < 4; ++kq) {
                int co = kq * 32 + g * 8;
                short8 bf = ldg8(Wm + co);
                #pragma unroll
                for (int mi = 0; mi < MR; ++mi) {
                    int ra = mi * 16 + r16;
                    short8 af = *(const short8*)(&OX[ra * 128 + (co & 64) + ((co & 63) ^ ((ra & 7) << 3))]);
                    hacc[mi][nf] = __builtin_amdgcn_mfma_f32_16x16x32_bf16(af, bf, hacc[mi][nf], 0, 0, 0);
                }
            }
        }
        #pragma unroll
        for (int nf = 0; nf < 8; ++nf) {
            int col = wv * 128 + nf * 16 + r16;
            float bv = b1[col];
            #pragma unroll
            for (int mi = 0; mi < MR; ++mi)
                #pragma unroll
                for (int r = 0; r < 4; ++r) {
                    int rowa = mi * 16 + g * 4 + r;
                    u2.hid[rowa * 512 + (col & 448) + ((col & 63) ^ ((rowa & 7) << 3))] =
                        f2bf(fmaxf(hacc[mi][nf][r] + bv, 0.f));
                }
        }
    }
    __syncthreads();

    // y = hid @ w2 (K=512)
    f32x4 yacc[MR][2] = {};
    #pragma unroll
    for (int q = 0; q < 2; ++q) {
        int ni = wv * 2 + q;
        const unsigned short* Wm = Wl + 131072 + (size_t)(ni * 16 + r16) * 512;
        #pragma unroll
        for (int kq = 0; kq < 16; ++kq) {
            int co = kq * 32 + g * 8;
            short8 bf = ldg8(Wm + co);
            #pragma unroll
            for (int mi = 0; mi < MR; ++mi) {
                int ra = mi * 16 + r16;
                short8 af = *(const short8*)(&u2.hid[ra * 512 + (co & 448) + ((co & 63) ^ ((ra & 7) << 3))]);
                yacc[mi][q] = __builtin_amdgcn_mfma_f32_16x16x32_bf16(af, bf, yacc[mi][q], 0, 0, 0);
            }
        }
    }
    __syncthreads();
    #pragma unroll
    for (int mi = 0; mi < MR; ++mi)
        #pragma unroll
        for (int q = 0; q < 2; ++q) {
            int ni = wv * 2 + q;
            float bv = b2[ni * 16 + r16];
            #pragma unroll
            for (int r = 0; r < 4; ++r)
                u2.Cs[(mi * 16 + g * 4 + r) * 132 + ni * 16 + r16] = yacc[mi][q][r] + bv;
        }
    __syncthreads();

    // LN2 (+residual xr)
    #pragma unroll
    for (int rr = 0; rr < RW; ++rr) {
        int row = wv * RW + rr;
        size_t go = (size_t)(row0 + row) * 128;
        float v0 = u2.Cs[row * 132 + lane] + xr[row * 132 + lane];
        float v1 = u2.Cs[row * 132 + 64 + lane] + xr[row * 132 + 64 + lane];
        float sum = v0 + v1, sq = v0 * v0 + v1 * v1;
        #pragma unroll
        for (int o2 = 32; o2 >= 1; o2 >>= 1) {
            sum += __shfl_xor(sum, o2);
            sq  += __shfl_xor(sq, o2);
        }
        float mu = sum * (1.f / 128.f);
        float var = sq * (1.f / 128.f) - mu * mu;
        float rs = rsqrtf(var + 1e-5f);
        float o0 = (v0 - mu) * rs * g2[lane] + be2[lane];
        float o1 = (v1 - mu) * rs * g2[lane + 64] + be2[lane + 64];
        if (!last) {
            x[go + lane] = o0;
            x[go + 64 + lane] = o1;
            xbf[go + lane] = f2bf(o0);
            xbf[go + 64 + lane] = f2bf(o1);
        } else {
            xr[row * 132 + lane] = o0;
            xr[row * 132 + 64 + lane] = o1;
        }
    }
    if (last) {
        __syncthreads();
        if (wv == 0) {
            float hj = cb1[lane];
            #pragma unroll 8
            for (int d = 0; d < 128; ++d)
                hj = fmaf(xr[(ROWS - 1) * 132 + d], cw1[d * 64 + lane], hj);
            hj = fmaxf(hj, 0.f);
            float acc = hj * cw2[lane];
            #pragma unroll
            for (int o2 = 32; o2 >= 1; o2 >>= 1) acc += __shfl_xor(acc, o2);
            if (lane == 0) outp[blockIdx.x] = acc + cb2[0];
        }
    }
}

// ================= Launch =====================================================
extern "C" void kernel_launch(void* const* d_in, const int* in_sizes, int n_in,
                              void* d_out, int out_size, void* d_ws, size_t ws_size,
                              hipStream_t stream) {
    (void)in_sizes; (void)n_in; (void)out_size; (void)ws_size;
    const float* cls_emb    = (const float*)d_in[0];
    const float* note_times = (const float*)d_in[1];
    const int*   note_counts= (const int*)d_in[2];
    const float* proj_w     = (const float*)d_in[3];
    const float* proj_b     = (const float*)d_in[4];
    const float* te_w       = (const float*)d_in[5];
    const float* te_b       = (const float*)d_in[6];
    const float* wq         = (const float*)d_in[7];
    const float* wk         = (const float*)d_in[8];
    const float* tf_wq      = (const float*)d_in[9];
    const float* tf_wk      = (const float*)d_in[10];
    const float* tf_wv      = (const float*)d_in[11];
    const float* tf_wo      = (const float*)d_in[12];
    const float* tf_ln1_g   = (const float*)d_in[13];
    const float* tf_ln1_b   = (const float*)d_in[14];
    const float* tf_w1      = (const float*)d_in[15];
    const float* tf_b1      = (const float*)d_in[16];
    const float* tf_w2      = (const float*)d_in[17];
    const float* tf_b2      = (const float*)d_in[18];
    const float* tf_ln2_g   = (const float*)d_in[19];
    const float* tf_ln2_b   = (const float*)d_in[20];
    const float* cls_w1     = (const float*)d_in[21];
    const float* cls_b1     = (const float*)d_in[22];
    const float* cls_w2     = (const float*)d_in[23];
    const float* cls_b2     = (const float*)d_in[24];
    float* out = (float*)d_out;
    float* ws = (float*)d_ws;

    // workspace layout (float units)
    unsigned short* note_emb16 = (unsigned short*)(ws + 0);       // 1,048,576 f
    float* x        = ws + 1048576;                                // 1,572,864 f
    unsigned short* obuf16 = (unsigned short*)(ws + 2621440);      // 786,432 f
    unsigned short* xbf    = (unsigned short*)(ws + 3407872);      // 786,432 f
    float* q_all    = ws + 4194304;                                // 3,072 f
    unsigned short* wt     = (unsigned short*)(ws + 4197376);      // 344,064 f

    TTab tab;
    int tile = 0, idx = 0;
    auto add = [&](const float* src, int dstOff, int K, int N) {
        tab.e[idx].src = src; tab.e[idx].dstOff = dstOff;
        tab.e[idx].K = K; tab.e[idx].N = N; tab.e[idx].tile0 = tile;
        tile += (K / 64) * (N / 64); ++idx;
    };
    add(proj_w, 0, DT_, DH_);
    int layerBase[NL_];
    for (int i = 0; i < NL_; ++i) {
        int base = 98304 + i * 196608;
        layerBase[i] = base;
        add(tf_wq + (size_t)i * DH_ * DH_, base,           DH_, DH_);
        add(tf_wk + (size_t)i * DH_ * DH_, base + 16384,   DH_, DH_);
        add(tf_wv + (size_t)i * DH_ * DH_, base + 32768,   DH_, DH_);
        add(tf_wo + (size_t)i * DH_ * DH_, base + 49152,   DH_, DH_);
        add(tf_w1 + (size_t)i * DH_ * DFF_, base + 65536,  DH_, DFF_);
        add(tf_w2 + (size_t)i * DFF_ * DH_, base + 131072, DFF_, DH_);
    }
    prep_weights_kernel<<<tile + 1, 256, 0, stream>>>(tab, tile, wt, te_w, te_b, wq, q_all);

    const int Mx = B_ * AL_; // 12288

    gemm_proj_kernel<<<(B_ * L_) / 32, 256, 0, stream>>>(
        cls_emb, wt, proj_b, note_emb16, B_ * L_, DH_, DT_);

    first_attn_kernel<<<B_ * 2, 256, 0, stream>>>(
        note_times, note_counts, te_w, te_b, wk, q_all, note_emb16, x, xbf);

    for (int i = 0; i < NL_; ++i) {
        int base = layerBase[i];
        int last = (i == NL_ - 1);
        attn2_kernel<<<B_ * 4, 192, 0, stream>>>(xbf, wt + base, obuf16);
        if (!last) {
            layer_tail_kernel<32><<<Mx / 32, 256, 0, stream>>>(
                obuf16, wt + base,
                tf_b1 + i * DFF_, tf_b2 + i * DH_,
                tf_ln1_g + i * DH_, tf_ln1_b + i * DH_,
                tf_ln2_g + i * DH_, tf_ln2_b + i * DH_,
                x, xbf,
                0, cls_w1, cls_b1, cls_w2, cls_b2, out);
        } else {
            layer_tail_kernel<16><<<B_, 256, 0, stream>>>(
                obuf16, wt + base,
                tf_b1 + i * DFF_, tf_b2 + i * DH_,
                tf_ln1_g + i * DH_, tf_ln1_b + i * DH_,
                tf_ln2_g + i * DH_, tf_ln2_b + i * DH_,
                x, xbf,
                1, cls_w1, cls_b1, cls_w2, cls_b2, out);
        }
    }
}